// Round 1
// baseline (649.367 us; speedup 1.0000x reference)
//
#include <hip/hip_runtime.h>
#include <hip/hip_bf16.h>

#define B_ 8192
#define D_ 3072
#define C_ 512
#define E_ 8

typedef float  floatx4 __attribute__((ext_vector_type(4)));
typedef __bf16 bf16x8  __attribute__((ext_vector_type(8)));
typedef __bf16 bf16x4  __attribute__((ext_vector_type(4)));

__device__ __forceinline__ bf16x4 cvt4(float4 v) {
    bf16x4 o;
    o[0] = (__bf16)v.x; o[1] = (__bf16)v.y; o[2] = (__bf16)v.z; o[3] = (__bf16)v.w;
    return o;
}

// async global->LDS, 16B per lane. LDS dest must be wave-uniform base + lane*16.
__device__ __forceinline__ void dma16(const void* g, void* l) {
    __builtin_amdgcn_global_load_lds(
        (const __attribute__((address_space(1))) unsigned int*)(uintptr_t)g,
        (__attribute__((address_space(3))) unsigned int*)(uintptr_t)l,
        16, 0, 0);
}

// ---------------- routing ----------------
__global__ void k_count(const int* __restrict__ label, int* __restrict__ counts) {
    int b = blockIdx.x * blockDim.x + threadIdx.x;
    if (b < B_) atomicAdd(&counts[label[b]], 1);
}

__global__ void k_offsets(const int* __restrict__ counts, int* __restrict__ offsets) {
    if (threadIdx.x == 0 && blockIdx.x == 0) {
        int s = 0;
        for (int e = 0; e < E_; ++e) { offsets[e] = s; s += counts[e]; }
    }
}

__global__ void k_scatter(const int* __restrict__ label, const int* __restrict__ offsets,
                          int* __restrict__ cursors, int* __restrict__ row_ids) {
    int b = blockIdx.x * blockDim.x + threadIdx.x;
    if (b < B_) {
        int e = label[b];
        int p = atomicAdd(&cursors[e], 1);
        row_ids[offsets[e] + p] = b;
    }
}

// ---------------- prepass: fp32 -> bf16 (img gathered to sorted order, weights) ----
#define D4_ (D_ / 4)
#define NI_ (B_ * D4_)          // img float4 count
#define NW_ (E_ * C_ * D4_)     // per-weight float4 count
__global__ __launch_bounds__(256)
void k_prep(const float4* __restrict__ img4, const int* __restrict__ row_ids,
            const float4* __restrict__ We4, const float4* __restrict__ Wd4,
            bf16x4* __restrict__ imgG4, bf16x4* __restrict__ We16_4,
            bf16x4* __restrict__ Wd16_4)
{
    int i = blockIdx.x * 256 + threadIdx.x;
    const int stride = gridDim.x * 256;
    const int total = NI_ + 2 * NW_;
    for (; i < total; i += stride) {
        if (i < NI_) {
            int row = i / D4_;
            int c   = i - row * D4_;
            float4 v = img4[(size_t)row_ids[row] * D4_ + c];
            imgG4[i] = cvt4(v);
        } else if (i < NI_ + NW_) {
            int j = i - NI_;
            We16_4[j] = cvt4(We4[j]);
        } else {
            int j = i - NI_ - NW_;
            Wd16_4[j] = cvt4(Wd4[j]);
        }
    }
}

// =====================================================================
// enc: code = relu(imgG @ We16^T + benc)
// 128x128 tile, BK=64, 512 thr = 8 waves (2M x 2N x 2Khalf), 64x64 wave-tile.
// 4-buffer LDS pipeline, prefetch depth 2, counted vmcnt(8), raw s_barrier,
// XOR-swizzled LDS (gran ^= row&7 on 128B rows) -> conflict-free ds_read_b128.
// =====================================================================
__global__ __launch_bounds__(512, 1)
void enc_kernel(const __bf16* __restrict__ imgG, const __bf16* __restrict__ We16,
                const float* __restrict__ benc, const int* __restrict__ counts,
                const int* __restrict__ offsets, __bf16* __restrict__ code)
{
    const int e   = blockIdx.z;
    const int cnt = counts[e];
    const int m0  = blockIdx.y * 128;
    if (m0 >= cnt) return;
    const int off = offsets[e];
    const int n0  = blockIdx.x * 128;

    __shared__ __align__(16) __bf16 As[4][128][64];   // 64 KB
    __shared__ __align__(16) __bf16 Bs[4][128][64];   // 64 KB

    const int tid  = threadIdx.x;
    const int lane = tid & 63;
    const int wave = tid >> 6;       // 0..7
    const int kh   = wave >> 2;      // 0..1 K-half
    const int wm   = (wave >> 1) & 1;
    const int wn   = wave & 1;

    // DMA geometry: per buffer, each thread loads 4x16B (A r0, A r1, B r0, B r1).
    // Linear LDS dest byte = r*8192 + tid*16 -> row = r*64 + (tid>>3), phys gran = tid&7.
    // Pre-swizzled global source col: gran_log = phys ^ (row&7).
    const int drow   = tid >> 3;                            // 0..63
    const int gcolsw = (((tid & 7) ^ (drow & 7)) << 3);     // swizzled col (elems, within 64)
    const __bf16* ag0 = imgG + (size_t)(off + m0 + drow) * D_ + gcolsw;
    const __bf16* ag1 = imgG + (size_t)(off + m0 + 64 + drow) * D_ + gcolsw;
    const __bf16* bg0 = We16 + ((size_t)e * C_ + n0 + drow) * D_ + gcolsw;
    const __bf16* bg1 = We16 + ((size_t)e * C_ + n0 + 64 + drow) * D_ + gcolsw;
    char* lA = (char*)As + tid * 16;
    char* lB = (char*)Bs + tid * 16;

#define STG(buf, step) do {                                     \
        const size_t ko_ = (size_t)(step) * 64;                 \
        char* la_ = lA + (buf) * 16384;                         \
        char* lb_ = lB + (buf) * 16384;                         \
        dma16(ag0 + ko_, la_);                                  \
        dma16(ag1 + ko_, la_ + 8192);                           \
        dma16(bg0 + ko_, lb_);                                  \
        dma16(bg1 + ko_, lb_ + 8192);                           \
    } while (0)

    STG(0, 0);
    STG(1, 1);

    floatx4 acc[4][4];
    #pragma unroll
    for (int i = 0; i < 4; ++i)
        #pragma unroll
        for (int j = 0; j < 4; ++j)
            acc[i][j] = (floatx4){0.f, 0.f, 0.f, 0.f};

    const int fr = lane & 15;
    const int g4 = lane >> 4;                            // 0..3
    const int gxor = (((kh * 4 + g4) ^ (fr & 7)) << 4);  // swizzled byte-in-row
    const char* Ab = (const char*)As + (wm * 64 + fr) * 128 + gxor;
    const char* Bb = (const char*)Bs + (wn * 64 + fr) * 128 + gxor;

    const int NS = D_ / 64;   // 48
    #pragma unroll 4
    for (int s = 0; s < NS; ++s) {
        const int pb = (s + 2) & 3;
        const int ps = (s + 2 < NS) ? (s + 2) : (NS - 1);   // clamp: keeps vmcnt uniform
        STG(pb, ps);
        asm volatile("s_waitcnt vmcnt(8)" ::: "memory");    // oldest stage (this buf) done
        __builtin_amdgcn_s_barrier();
        asm volatile("" ::: "memory");
        __builtin_amdgcn_sched_barrier(0);
        const char* pA = Ab + (s & 3) * 16384;
        const char* pB = Bb + (s & 3) * 16384;
        bf16x8 af[4], bq[4];
        #pragma unroll
        for (int i = 0; i < 4; ++i) {
            af[i] = *(const bf16x8*)(pA + i * 2048);
            bq[i] = *(const bf16x8*)(pB + i * 2048);
        }
        __builtin_amdgcn_s_setprio(1);
        #pragma unroll
        for (int mt = 0; mt < 4; ++mt)
            #pragma unroll
            for (int nt = 0; nt < 4; ++nt)
                acc[mt][nt] = __builtin_amdgcn_mfma_f32_16x16x32_bf16(af[mt], bq[nt], acc[mt][nt], 0, 0, 0);
        __builtin_amdgcn_s_setprio(0);
    }
#undef STG

    // ---- K-half reduce via LDS (symmetric exchange), then split epilogue ----
    __syncthreads();   // drains leftover clamped DMAs + all LDS reads done
    {
        floatx4* dst = (floatx4*)(kh == 0 ? (void*)Bs : (void*)As) + (wave & 3) * 1024;
        #pragma unroll
        for (int mt = 0; mt < 4; ++mt)
            #pragma unroll
            for (int nt = 0; nt < 4; ++nt)
                dst[(mt * 4 + nt) * 64 + lane] = acc[mt][nt];
    }
    __syncthreads();
    {
        const floatx4* src = (const floatx4*)(kh == 0 ? (void*)As : (void*)Bs) + (wave & 3) * 1024;
        #pragma unroll
        for (int mt = 0; mt < 4; ++mt)
            #pragma unroll
            for (int nt = 0; nt < 4; ++nt)
                acc[mt][nt] += src[(mt * 4 + nt) * 64 + lane];
    }
    const int rq = g4 << 2;
    #pragma unroll
    for (int nth = 0; nth < 2; ++nth) {
        const int nt = kh * 2 + nth;   // kh0: nt 0,1  kh1: nt 2,3
        const int gcol = n0 + wn * 64 + nt * 16 + fr;
        const float bias = benc[e * C_ + gcol];
        #pragma unroll
        for (int mt = 0; mt < 4; ++mt)
            #pragma unroll
            for (int reg = 0; reg < 4; ++reg) {
                const int g = m0 + wm * 64 + mt * 16 + rq + reg;
                if (g < cnt) {
                    float v = acc[mt][nt][reg] + bias;
                    v = v > 0.f ? v : 0.f;
                    code[(size_t)(off + g) * C_ + gcol] = (__bf16)v;
                }
            }
    }
}

// =====================================================================
// dec: dec = code @ Wd16^T + bdec, scatter + fused loss. Same template, K=512.
// =====================================================================
__global__ __launch_bounds__(512, 1)
void dec_kernel(const __bf16* __restrict__ imgG, const __bf16* __restrict__ Wd16,
                const float* __restrict__ bdec, const int* __restrict__ row_ids,
                const int* __restrict__ counts, const int* __restrict__ offsets,
                const __bf16* __restrict__ code, float* __restrict__ decoded,
                double* __restrict__ loss_acc)
{
    const int e   = blockIdx.z;
    const int cnt = counts[e];
    const int m0  = blockIdx.y * 128;
    if (m0 >= cnt) return;
    const int off = offsets[e];
    const int n0  = blockIdx.x * 128;

    __shared__ __align__(16) __bf16 As[4][128][64];
    __shared__ __align__(16) __bf16 Bs[4][128][64];
    __shared__ float red2[8];

    const int tid  = threadIdx.x;
    const int lane = tid & 63;
    const int wave = tid >> 6;
    const int kh   = wave >> 2;
    const int wm   = (wave >> 1) & 1;
    const int wn   = wave & 1;

    const int drow   = tid >> 3;
    const int gcolsw = (((tid & 7) ^ (drow & 7)) << 3);
    const __bf16* ag0 = code + (size_t)(off + m0 + drow) * C_ + gcolsw;
    const __bf16* ag1 = code + (size_t)(off + m0 + 64 + drow) * C_ + gcolsw;
    const __bf16* bg0 = Wd16 + ((size_t)e * D_ + n0 + drow) * C_ + gcolsw;
    const __bf16* bg1 = Wd16 + ((size_t)e * D_ + n0 + 64 + drow) * C_ + gcolsw;
    char* lA = (char*)As + tid * 16;
    char* lB = (char*)Bs + tid * 16;

#define STG(buf, step) do {                                     \
        const size_t ko_ = (size_t)(step) * 64;                 \
        char* la_ = lA + (buf) * 16384;                         \
        char* lb_ = lB + (buf) * 16384;                         \
        dma16(ag0 + ko_, la_);                                  \
        dma16(ag1 + ko_, la_ + 8192);                           \
        dma16(bg0 + ko_, lb_);                                  \
        dma16(bg1 + ko_, lb_ + 8192);                           \
    } while (0)

    STG(0, 0);
    STG(1, 1);

    floatx4 acc[4][4];
    #pragma unroll
    for (int i = 0; i < 4; ++i)
        #pragma unroll
        for (int j = 0; j < 4; ++j)
            acc[i][j] = (floatx4){0.f, 0.f, 0.f, 0.f};

    const int fr = lane & 15;
    const int g4 = lane >> 4;
    const int gxor = (((kh * 4 + g4) ^ (fr & 7)) << 4);
    const char* Ab = (const char*)As + (wm * 64 + fr) * 128 + gxor;
    const char* Bb = (const char*)Bs + (wn * 64 + fr) * 128 + gxor;

    const int NS = C_ / 64;   // 8
    #pragma unroll 4
    for (int s = 0; s < NS; ++s) {
        const int pb = (s + 2) & 3;
        const int ps = (s + 2 < NS) ? (s + 2) : (NS - 1);
        STG(pb, ps);
        asm volatile("s_waitcnt vmcnt(8)" ::: "memory");
        __builtin_amdgcn_s_barrier();
        asm volatile("" ::: "memory");
        __builtin_amdgcn_sched_barrier(0);
        const char* pA = Ab + (s & 3) * 16384;
        const char* pB = Bb + (s & 3) * 16384;
        bf16x8 af[4], bq[4];
        #pragma unroll
        for (int i = 0; i < 4; ++i) {
            af[i] = *(const bf16x8*)(pA + i * 2048);
            bq[i] = *(const bf16x8*)(pB + i * 2048);
        }
        __builtin_amdgcn_s_setprio(1);
        #pragma unroll
        for (int mt = 0; mt < 4; ++mt)
            #pragma unroll
            for (int nt = 0; nt < 4; ++nt)
                acc[mt][nt] = __builtin_amdgcn_mfma_f32_16x16x32_bf16(af[mt], bq[nt], acc[mt][nt], 0, 0, 0);
        __builtin_amdgcn_s_setprio(0);
    }
#undef STG

    __syncthreads();
    {
        floatx4* dst = (floatx4*)(kh == 0 ? (void*)Bs : (void*)As) + (wave & 3) * 1024;
        #pragma unroll
        for (int mt = 0; mt < 4; ++mt)
            #pragma unroll
            for (int nt = 0; nt < 4; ++nt)
                dst[(mt * 4 + nt) * 64 + lane] = acc[mt][nt];
    }
    __syncthreads();
    {
        const floatx4* src = (const floatx4*)(kh == 0 ? (void*)As : (void*)Bs) + (wave & 3) * 1024;
        #pragma unroll
        for (int mt = 0; mt < 4; ++mt)
            #pragma unroll
            for (int nt = 0; nt < 4; ++nt)
                acc[mt][nt] += src[(mt * 4 + nt) * 64 + lane];
    }

    const int rq = g4 << 2;
    int orig[4][4];
    #pragma unroll
    for (int mt = 0; mt < 4; ++mt)
        #pragma unroll
        for (int reg = 0; reg < 4; ++reg) {
            const int g = m0 + wm * 64 + mt * 16 + rq + reg;
            orig[mt][reg] = (g < cnt) ? row_ids[off + g] : -1;
        }

    float lsum = 0.f;
    #pragma unroll
    for (int nth = 0; nth < 2; ++nth) {
        const int nt = kh * 2 + nth;
        const int gcol = n0 + wn * 64 + nt * 16 + fr;
        const float bias = bdec[e * D_ + gcol];
        #pragma unroll
        for (int mt = 0; mt < 4; ++mt)
            #pragma unroll
            for (int reg = 0; reg < 4; ++reg) {
                if (orig[mt][reg] >= 0) {
                    const int g = m0 + wm * 64 + mt * 16 + rq + reg;
                    float v = acc[mt][nt][reg] + bias;
                    decoded[(size_t)orig[mt][reg] * D_ + gcol] = v;
                    float d = v - (float)imgG[(size_t)(off + g) * D_ + gcol];
                    lsum += d * d;
                }
            }
    }
    #pragma unroll
    for (int o = 32; o > 0; o >>= 1) lsum += __shfl_down(lsum, o, 64);
    if (lane == 0) red2[wave] = lsum;
    __syncthreads();
    if (tid == 0) {
        double t = 0.0;
        #pragma unroll
        for (int w = 0; w < 8; ++w) t += (double)red2[w];
        atomicAdd(loss_acc, t);
    }
}

__global__ void k_final(const double* __restrict__ loss_acc, float* __restrict__ out) {
    if (threadIdx.x == 0 && blockIdx.x == 0)
        out[0] = (float)(*loss_acc / (double)((size_t)B_ * (size_t)D_));
}

// ---------------- launch ----------------
extern "C" void kernel_launch(void* const* d_in, const int* in_sizes, int n_in,
                              void* d_out, int out_size, void* d_ws, size_t ws_size,
                              hipStream_t stream)
{
    const float* img   = (const float*)d_in[0];
    const int*   label = (const int*)d_in[1];
    const float* Wenc  = (const float*)d_in[2];
    const float* benc  = (const float*)d_in[3];
    const float* Wdec  = (const float*)d_in[4];
    const float* bdec  = (const float*)d_in[5];
    float* out = (float*)d_out;

    char* ws = (char*)d_ws;
    int*    counts  = (int*)(ws + 0);
    int*    cursors = (int*)(ws + 32);
    int*    offsets = (int*)(ws + 64);
    double* loss    = (double*)(ws + 96);
    int*    row_ids = (int*)(ws + 128);
    // bf16 scratch (sizes include 128 rows of tail slack for OOB tile reads):
    __bf16* code = (__bf16*)(ws + 65536);                               // (B+128)*C*2 = 8,519,680
    __bf16* imgG = (__bf16*)(ws + 65536 + 8519680);                     // (B+128)*D*2 = 51,118,080
    __bf16* We16 = (__bf16*)(ws + 65536 + 8519680 + 51118080);          // E*C*D*2 = 25,165,824
    __bf16* Wd16 = (__bf16*)(ws + 65536 + 8519680 + 51118080 + 25165824);
    // total ws use ~105 MB

    hipMemsetAsync(d_ws, 0, 128, stream);
    k_count  <<<dim3(B_ / 256), dim3(256), 0, stream>>>(label, counts);
    k_offsets<<<dim3(1),        dim3(64),  0, stream>>>(counts, offsets);
    k_scatter<<<dim3(B_ / 256), dim3(256), 0, stream>>>(label, offsets, cursors, row_ids);
    k_prep   <<<dim3(2048),     dim3(256), 0, stream>>>(
        (const float4*)img, row_ids, (const float4*)Wenc, (const float4*)Wdec,
        (bf16x4*)imgG, (bf16x4*)We16, (bf16x4*)Wd16);
    enc_kernel<<<dim3(C_ / 128, B_ / 128, E_), dim3(512), 0, stream>>>(
        imgG, We16, benc, counts, offsets, code);
    dec_kernel<<<dim3(D_ / 128, B_ / 128, E_), dim3(512), 0, stream>>>(
        imgG, Wd16, bdec, row_ids, counts, offsets, code, out + 1, loss);
    k_final<<<dim3(1), dim3(64), 0, stream>>>(loss, out);
}

// Round 2
// 533.074 us; speedup vs baseline: 1.2182x; 1.2182x over previous
//
#include <hip/hip_runtime.h>
#include <hip/hip_bf16.h>

#define B_ 8192
#define D_ 3072
#define C_ 512
#define E_ 8

typedef float  floatx4 __attribute__((ext_vector_type(4)));
typedef __bf16 bf16x8  __attribute__((ext_vector_type(8)));
typedef __bf16 bf16x4  __attribute__((ext_vector_type(4)));

__device__ __forceinline__ bf16x4 cvt4(float4 v) {
    bf16x4 o;
    o[0] = (__bf16)v.x; o[1] = (__bf16)v.y; o[2] = (__bf16)v.z; o[3] = (__bf16)v.w;
    return o;
}

// async global->LDS, 16B per lane. LDS dest must be wave-uniform base + lane*16.
__device__ __forceinline__ void dma16(const void* g, void* l) {
    __builtin_amdgcn_global_load_lds(
        (const __attribute__((address_space(1))) unsigned int*)(uintptr_t)g,
        (__attribute__((address_space(3))) unsigned int*)(uintptr_t)l,
        16, 0, 0);
}

// ---------------- routing ----------------
__global__ void k_count(const int* __restrict__ label, int* __restrict__ counts) {
    int b = blockIdx.x * blockDim.x + threadIdx.x;
    if (b < B_) atomicAdd(&counts[label[b]], 1);
}

__global__ void k_offsets(const int* __restrict__ counts, int* __restrict__ offsets) {
    if (threadIdx.x == 0 && blockIdx.x == 0) {
        int s = 0;
        for (int e = 0; e < E_; ++e) { offsets[e] = s; s += counts[e]; }
    }
}

__global__ void k_scatter(const int* __restrict__ label, const int* __restrict__ offsets,
                          int* __restrict__ cursors, int* __restrict__ row_ids) {
    int b = blockIdx.x * blockDim.x + threadIdx.x;
    if (b < B_) {
        int e = label[b];
        int p = atomicAdd(&cursors[e], 1);
        row_ids[offsets[e] + p] = b;
    }
}

// ---------------- prepass: fp32 -> bf16 (img gathered to sorted order, weights) ----
#define D4_ (D_ / 4)
#define NI_ (B_ * D4_)          // img float4 count
#define NW_ (E_ * C_ * D4_)     // per-weight float4 count
__global__ __launch_bounds__(256)
void k_prep(const float4* __restrict__ img4, const int* __restrict__ row_ids,
            const float4* __restrict__ We4, const float4* __restrict__ Wd4,
            bf16x4* __restrict__ imgG4, bf16x4* __restrict__ We16_4,
            bf16x4* __restrict__ Wd16_4)
{
    int i = blockIdx.x * 256 + threadIdx.x;
    const int stride = gridDim.x * 256;
    const int total = NI_ + 2 * NW_;
    for (; i < total; i += stride) {
        if (i < NI_) {
            int row = i / D4_;
            int c   = i - row * D4_;
            float4 v = img4[(size_t)row_ids[row] * D4_ + c];
            imgG4[i] = cvt4(v);
        } else if (i < NI_ + NW_) {
            int j = i - NI_;
            We16_4[j] = cvt4(We4[j]);
        } else {
            int j = i - NI_ - NW_;
            Wd16_4[j] = cvt4(Wd4[j]);
        }
    }
}

// =====================================================================
// Shared GEMM template: 128x128 tile, BK=32, 256 thr = 4 waves (2Mx2N),
// 64x64 wave-tile, 4-buffer LDS (2x32KB total -> 2 blocks/CU),
// depth-2 prefetch, counted vmcnt(8), one raw s_barrier per K-step,
// XOR-swizzled 64B LDS rows (granule ^= (row>>1)&3): 2-way reads (~free).
// Swizzle applied on BOTH sides: pre-swizzled global source col for the
// linear DMA dest, matching swizzled ds_read address (rule #21).
// =====================================================================

// enc: code = relu(imgG @ We16^T + benc)
__global__ __launch_bounds__(256, 2)
void enc_kernel(const __bf16* __restrict__ imgG, const __bf16* __restrict__ We16,
                const float* __restrict__ benc, const int* __restrict__ counts,
                const int* __restrict__ offsets, __bf16* __restrict__ code)
{
    const int e   = blockIdx.z;
    const int cnt = counts[e];
    const int m0  = blockIdx.y * 128;
    if (m0 >= cnt) return;
    const int off = offsets[e];
    const int n0  = blockIdx.x * 128;

    __shared__ __align__(16) __bf16 As[4][128][32];   // 32 KB
    __shared__ __align__(16) __bf16 Bs[4][128][32];   // 32 KB

    const int tid  = threadIdx.x;
    const int lane = tid & 63;
    const int wave = tid >> 6;    // 0..3
    const int wm   = wave >> 1;
    const int wn   = wave & 1;

    // DMA: per 4KB round, row = tid>>2 (0..63), phys granule = tid&3.
    // Source col pre-swizzled: g_log = (tid&3) ^ ((row>>1)&3) = (tid&3)^((tid>>3)&3).
    const int drow = tid >> 2;
    const int gsw  = (((tid & 3) ^ ((tid >> 3) & 3)) << 3);  // elems
    const __bf16* ag0 = imgG + (size_t)(off + m0 + drow) * D_ + gsw;
    const __bf16* ag1 = ag0 + (size_t)64 * D_;
    const __bf16* bg0 = We16 + ((size_t)e * C_ + n0 + drow) * D_ + gsw;
    const __bf16* bg1 = bg0 + (size_t)64 * D_;
    char* lA = (char*)As + tid * 16;
    char* lB = (char*)Bs + tid * 16;

#define STG(buf, step) do {                                  \
        const size_t ko_ = (size_t)(step) * 32;              \
        dma16(ag0 + ko_, lA + (buf) * 8192);                 \
        dma16(ag1 + ko_, lA + (buf) * 8192 + 4096);          \
        dma16(bg0 + ko_, lB + (buf) * 8192);                 \
        dma16(bg1 + ko_, lB + (buf) * 8192 + 4096);          \
    } while (0)

    STG(0, 0);
    STG(1, 1);

    floatx4 acc[4][4];
    #pragma unroll
    for (int i = 0; i < 4; ++i)
        #pragma unroll
        for (int j = 0; j < 4; ++j)
            acc[i][j] = (floatx4){0.f, 0.f, 0.f, 0.f};

    const int fr = lane & 15;
    const int g4 = lane >> 4;                       // 0..3, logical k-granule
    const int psw = ((g4 ^ ((fr >> 1) & 3)) << 4);  // physical granule byte offset
    const char* Ab = (const char*)As + (wm * 64 + fr) * 64 + psw;
    const char* Bb = (const char*)Bs + (wn * 64 + fr) * 64 + psw;

    const int NS = D_ / 32;   // 96
    #pragma unroll 4
    for (int s = 0; s < NS; ++s) {
        const int pb = (s + 2) & 3;
        const int ps = (s + 2 < NS) ? (s + 2) : (NS - 1);   // clamp keeps vmcnt uniform
        STG(pb, ps);
        asm volatile("s_waitcnt vmcnt(8)" ::: "memory");    // buffer s's 4 DMAs done
        __builtin_amdgcn_s_barrier();
        asm volatile("" ::: "memory");
        __builtin_amdgcn_sched_barrier(0);
        const char* pA = Ab + (s & 3) * 8192;
        const char* pB = Bb + (s & 3) * 8192;
        bf16x8 af[4], bq[4];
        #pragma unroll
        for (int i = 0; i < 4; ++i) {
            af[i] = *(const bf16x8*)(pA + i * 1024);
            bq[i] = *(const bf16x8*)(pB + i * 1024);
        }
        __builtin_amdgcn_s_setprio(1);
        #pragma unroll
        for (int mt = 0; mt < 4; ++mt)
            #pragma unroll
            for (int nt = 0; nt < 4; ++nt)
                acc[mt][nt] = __builtin_amdgcn_mfma_f32_16x16x32_bf16(af[mt], bq[nt], acc[mt][nt], 0, 0, 0);
        __builtin_amdgcn_s_setprio(0);
    }
#undef STG
    asm volatile("s_waitcnt vmcnt(0)" ::: "memory");   // drain clamped tail DMAs

    const int rq = g4 << 2;
    #pragma unroll
    for (int nt = 0; nt < 4; ++nt) {
        const int gcol = n0 + wn * 64 + nt * 16 + fr;
        const float bias = benc[e * C_ + gcol];
        #pragma unroll
        for (int mt = 0; mt < 4; ++mt)
            #pragma unroll
            for (int reg = 0; reg < 4; ++reg) {
                const int g = m0 + wm * 64 + mt * 16 + rq + reg;
                if (g < cnt) {
                    float v = acc[mt][nt][reg] + bias;
                    v = v > 0.f ? v : 0.f;
                    code[(size_t)(off + g) * C_ + gcol] = (__bf16)v;
                }
            }
    }
}

// dec: dec = code @ Wd16^T + bdec, scatter to original rows + fused loss
__global__ __launch_bounds__(256, 2)
void dec_kernel(const __bf16* __restrict__ imgG, const __bf16* __restrict__ Wd16,
                const float* __restrict__ bdec, const int* __restrict__ row_ids,
                const int* __restrict__ counts, const int* __restrict__ offsets,
                const __bf16* __restrict__ code, float* __restrict__ decoded,
                double* __restrict__ loss_acc)
{
    const int e   = blockIdx.z;
    const int cnt = counts[e];
    const int m0  = blockIdx.y * 128;
    if (m0 >= cnt) return;
    const int off = offsets[e];
    const int n0  = blockIdx.x * 128;

    __shared__ __align__(16) __bf16 As[4][128][32];
    __shared__ __align__(16) __bf16 Bs[4][128][32];
    __shared__ float red[4];

    const int tid  = threadIdx.x;
    const int lane = tid & 63;
    const int wave = tid >> 6;
    const int wm   = wave >> 1;
    const int wn   = wave & 1;

    const int drow = tid >> 2;
    const int gsw  = (((tid & 3) ^ ((tid >> 3) & 3)) << 3);
    const __bf16* ag0 = code + (size_t)(off + m0 + drow) * C_ + gsw;
    const __bf16* ag1 = ag0 + (size_t)64 * C_;
    const __bf16* bg0 = Wd16 + ((size_t)e * D_ + n0 + drow) * C_ + gsw;
    const __bf16* bg1 = bg0 + (size_t)64 * C_;
    char* lA = (char*)As + tid * 16;
    char* lB = (char*)Bs + tid * 16;

#define STG(buf, step) do {                                  \
        const size_t ko_ = (size_t)(step) * 32;              \
        dma16(ag0 + ko_, lA + (buf) * 8192);                 \
        dma16(ag1 + ko_, lA + (buf) * 8192 + 4096);          \
        dma16(bg0 + ko_, lB + (buf) * 8192);                 \
        dma16(bg1 + ko_, lB + (buf) * 8192 + 4096);          \
    } while (0)

    STG(0, 0);
    STG(1, 1);

    floatx4 acc[4][4];
    #pragma unroll
    for (int i = 0; i < 4; ++i)
        #pragma unroll
        for (int j = 0; j < 4; ++j)
            acc[i][j] = (floatx4){0.f, 0.f, 0.f, 0.f};

    const int fr = lane & 15;
    const int g4 = lane >> 4;
    const int psw = ((g4 ^ ((fr >> 1) & 3)) << 4);
    const char* Ab = (const char*)As + (wm * 64 + fr) * 64 + psw;
    const char* Bb = (const char*)Bs + (wn * 64 + fr) * 64 + psw;

    const int NS = C_ / 32;   // 16
    #pragma unroll 4
    for (int s = 0; s < NS; ++s) {
        const int pb = (s + 2) & 3;
        const int ps = (s + 2 < NS) ? (s + 2) : (NS - 1);
        STG(pb, ps);
        asm volatile("s_waitcnt vmcnt(8)" ::: "memory");
        __builtin_amdgcn_s_barrier();
        asm volatile("" ::: "memory");
        __builtin_amdgcn_sched_barrier(0);
        const char* pA = Ab + (s & 3) * 8192;
        const char* pB = Bb + (s & 3) * 8192;
        bf16x8 af[4], bq[4];
        #pragma unroll
        for (int i = 0; i < 4; ++i) {
            af[i] = *(const bf16x8*)(pA + i * 1024);
            bq[i] = *(const bf16x8*)(pB + i * 1024);
        }
        __builtin_amdgcn_s_setprio(1);
        #pragma unroll
        for (int mt = 0; mt < 4; ++mt)
            #pragma unroll
            for (int nt = 0; nt < 4; ++nt)
                acc[mt][nt] = __builtin_amdgcn_mfma_f32_16x16x32_bf16(af[mt], bq[nt], acc[mt][nt], 0, 0, 0);
        __builtin_amdgcn_s_setprio(0);
    }
#undef STG
    asm volatile("s_waitcnt vmcnt(0)" ::: "memory");

    const int rq = g4 << 2;
    int orig[4][4];
    #pragma unroll
    for (int mt = 0; mt < 4; ++mt)
        #pragma unroll
        for (int reg = 0; reg < 4; ++reg) {
            const int g = m0 + wm * 64 + mt * 16 + rq + reg;
            orig[mt][reg] = (g < cnt) ? row_ids[off + g] : -1;
        }

    float lsum = 0.f;
    #pragma unroll
    for (int nt = 0; nt < 4; ++nt) {
        const int gcol = n0 + wn * 64 + nt * 16 + fr;
        const float bias = bdec[e * D_ + gcol];
        #pragma unroll
        for (int mt = 0; mt < 4; ++mt)
            #pragma unroll
            for (int reg = 0; reg < 4; ++reg) {
                if (orig[mt][reg] >= 0) {
                    const int g = m0 + wm * 64 + mt * 16 + rq + reg;
                    float v = acc[mt][nt][reg] + bias;
                    decoded[(size_t)orig[mt][reg] * D_ + gcol] = v;
                    float d = v - (float)imgG[(size_t)(off + g) * D_ + gcol];
                    lsum += d * d;
                }
            }
    }
    #pragma unroll
    for (int o = 32; o > 0; o >>= 1) lsum += __shfl_down(lsum, o, 64);
    if (lane == 0) red[wave] = lsum;
    __syncthreads();
    if (tid == 0) atomicAdd(loss_acc, (double)(red[0] + red[1] + red[2] + red[3]));
}

__global__ void k_final(const double* __restrict__ loss_acc, float* __restrict__ out) {
    if (threadIdx.x == 0 && blockIdx.x == 0)
        out[0] = (float)(*loss_acc / (double)((size_t)B_ * (size_t)D_));
}

// ---------------- launch ----------------
extern "C" void kernel_launch(void* const* d_in, const int* in_sizes, int n_in,
                              void* d_out, int out_size, void* d_ws, size_t ws_size,
                              hipStream_t stream)
{
    const float* img   = (const float*)d_in[0];
    const int*   label = (const int*)d_in[1];
    const float* Wenc  = (const float*)d_in[2];
    const float* benc  = (const float*)d_in[3];
    const float* Wdec  = (const float*)d_in[4];
    const float* bdec  = (const float*)d_in[5];
    float* out = (float*)d_out;

    char* ws = (char*)d_ws;
    int*    counts  = (int*)(ws + 0);
    int*    cursors = (int*)(ws + 32);
    int*    offsets = (int*)(ws + 64);
    double* loss    = (double*)(ws + 96);
    int*    row_ids = (int*)(ws + 128);
    // bf16 scratch (sizes include 128 rows of tail slack for OOB tile reads):
    __bf16* code = (__bf16*)(ws + 65536);                               // (B+128)*C*2 = 8,519,680
    __bf16* imgG = (__bf16*)(ws + 65536 + 8519680);                     // (B+128)*D*2 = 51,118,080
    __bf16* We16 = (__bf16*)(ws + 65536 + 8519680 + 51118080);          // E*C*D*2 = 25,165,824
    __bf16* Wd16 = (__bf16*)(ws + 65536 + 8519680 + 51118080 + 25165824);
    // total ws use ~105 MB

    hipMemsetAsync(d_ws, 0, 128, stream);
    k_count  <<<dim3(B_ / 256), dim3(256), 0, stream>>>(label, counts);
    k_offsets<<<dim3(1),        dim3(64),  0, stream>>>(counts, offsets);
    k_scatter<<<dim3(B_ / 256), dim3(256), 0, stream>>>(label, offsets, cursors, row_ids);
    k_prep   <<<dim3(2048),     dim3(256), 0, stream>>>(
        (const float4*)img, row_ids, (const float4*)Wenc, (const float4*)Wdec,
        (bf16x4*)imgG, (bf16x4*)We16, (bf16x4*)Wd16);
    enc_kernel<<<dim3(C_ / 128, B_ / 128, E_), dim3(256), 0, stream>>>(
        imgG, We16, benc, counts, offsets, code);
    dec_kernel<<<dim3(D_ / 128, B_ / 128, E_), dim3(256), 0, stream>>>(
        imgG, Wd16, bdec, row_ids, counts, offsets, code, out + 1, loss);
    k_final<<<dim3(1), dim3(64), 0, stream>>>(loss, out);
}

// Round 3
// 523.821 us; speedup vs baseline: 1.2397x; 1.0177x over previous
//
#include <hip/hip_runtime.h>
#include <hip/hip_bf16.h>

#define B_ 8192
#define D_ 3072
#define C_ 512
#define E_ 8

typedef float  floatx4 __attribute__((ext_vector_type(4)));
typedef __bf16 bf16x8  __attribute__((ext_vector_type(8)));
typedef __bf16 bf16x4  __attribute__((ext_vector_type(4)));

__device__ __forceinline__ bf16x4 cvt4(float4 v) {
    bf16x4 o;
    o[0] = (__bf16)v.x; o[1] = (__bf16)v.y; o[2] = (__bf16)v.z; o[3] = (__bf16)v.w;
    return o;
}

// async global->LDS, 16B per lane. LDS dest must be wave-uniform base + lane*16.
__device__ __forceinline__ void dma16(const void* g, void* l) {
    __builtin_amdgcn_global_load_lds(
        (const __attribute__((address_space(1))) unsigned int*)(uintptr_t)g,
        (__attribute__((address_space(3))) unsigned int*)(uintptr_t)l,
        16, 0, 0);
}

// ---------------- routing ----------------
__global__ void k_count(const int* __restrict__ label, int* __restrict__ counts) {
    int b = blockIdx.x * blockDim.x + threadIdx.x;
    if (b < B_) atomicAdd(&counts[label[b]], 1);
}

__global__ void k_offsets(const int* __restrict__ counts, int* __restrict__ offsets) {
    if (threadIdx.x == 0 && blockIdx.x == 0) {
        int s = 0;
        for (int e = 0; e < E_; ++e) { offsets[e] = s; s += counts[e]; }
    }
}

__global__ void k_scatter(const int* __restrict__ label, const int* __restrict__ offsets,
                          int* __restrict__ cursors, int* __restrict__ row_ids) {
    int b = blockIdx.x * blockDim.x + threadIdx.x;
    if (b < B_) {
        int e = label[b];
        int p = atomicAdd(&cursors[e], 1);
        row_ids[offsets[e] + p] = b;
    }
}

// ---------------- prepass: fp32 -> bf16 (img gathered to sorted order, weights) ----
#define D4_ (D_ / 4)
#define NI_ (B_ * D4_)          // img float4 count
#define NW_ (E_ * C_ * D4_)     // per-weight float4 count
__global__ __launch_bounds__(256)
void k_prep(const float4* __restrict__ img4, const int* __restrict__ row_ids,
            const float4* __restrict__ We4, const float4* __restrict__ Wd4,
            bf16x4* __restrict__ imgG4, bf16x4* __restrict__ We16_4,
            bf16x4* __restrict__ Wd16_4)
{
    int i = blockIdx.x * 256 + threadIdx.x;
    const int stride = gridDim.x * 256;
    const int total = NI_ + 2 * NW_;
    for (; i < total; i += stride) {
        if (i < NI_) {
            int row = i / D4_;
            int c   = i - row * D4_;
            float4 v = img4[(size_t)row_ids[row] * D4_ + c];
            imgG4[i] = cvt4(v);
        } else if (i < NI_ + NW_) {
            int j = i - NI_;
            We16_4[j] = cvt4(We4[j]);
        } else {
            int j = i - NI_ - NW_;
            Wd16_4[j] = cvt4(Wd4[j]);
        }
    }
}

// =====================================================================
// enc: code = relu(imgG @ We16^T + benc)
// 64x128 tile (BMx BN), BK=32, 256 thr = 4 waves (2Mx2N), wave-tile 32x64.
// 4-buffer LDS (48 KB), prefetch distance d=3, vmcnt(6) steady state.
// Ordering per step: vmcnt (own DMAs of buf s done) -> s_barrier (all waves'
// DMAs landed AND all reads of buf s-1 retired) -> STG(s+3) (overwrites
// buf s-1: safe) -> ds_read buf s -> MFMA.
// Grid split to BM=64 so 528 blocks ~ 2/CU co-residency: window k*d*step ~780cy.
// =====================================================================
__global__ __launch_bounds__(256, 3)
void enc_kernel(const __bf16* __restrict__ imgG, const __bf16* __restrict__ We16,
                const float* __restrict__ benc, const int* __restrict__ counts,
                const int* __restrict__ offsets, __bf16* __restrict__ code)
{
    const int e   = blockIdx.z;
    const int cnt = counts[e];
    const int m0  = blockIdx.y * 64;
    if (m0 >= cnt) return;
    const int off = offsets[e];
    const int n0  = blockIdx.x * 128;

    __shared__ __align__(16) __bf16 As[4][64][32];    // 16 KB
    __shared__ __align__(16) __bf16 Bs[4][128][32];   // 32 KB

    const int tid  = threadIdx.x;
    const int lane = tid & 63;
    const int wave = tid >> 6;    // 0..3
    const int wm   = wave >> 1;
    const int wn   = wave & 1;

    // DMA: row = tid>>2 (0..63), phys granule = tid&3; source col pre-swizzled.
    const int drow = tid >> 2;
    const int gsw  = (((tid & 3) ^ ((tid >> 3) & 3)) << 3);  // elems
    const __bf16* ag0 = imgG + (size_t)(off + m0 + drow) * D_ + gsw;
    const __bf16* bg0 = We16 + ((size_t)e * C_ + n0 + drow) * D_ + gsw;
    const __bf16* bg1 = bg0 + (size_t)64 * D_;
    char* lA = (char*)As + tid * 16;
    char* lB = (char*)Bs + tid * 16;

#define STG(buf, step) do {                                  \
        const size_t ko_ = (size_t)(step) * 32;              \
        dma16(ag0 + ko_, lA + (buf) * 4096);                 \
        dma16(bg0 + ko_, lB + (buf) * 8192);                 \
        dma16(bg1 + ko_, lB + (buf) * 8192 + 4096);          \
    } while (0)

    STG(0, 0);
    STG(1, 1);
    STG(2, 2);

    floatx4 acc[2][4];
    #pragma unroll
    for (int i = 0; i < 2; ++i)
        #pragma unroll
        for (int j = 0; j < 4; ++j)
            acc[i][j] = (floatx4){0.f, 0.f, 0.f, 0.f};

    const int fr = lane & 15;
    const int g4 = lane >> 4;                       // 0..3, logical k-granule
    const int psw = ((g4 ^ ((fr >> 1) & 3)) << 4);  // physical granule byte offset
    const char* Ab = (const char*)As + (wm * 32 + fr) * 64 + psw;
    const char* Bb = (const char*)Bs + (wn * 64 + fr) * 64 + psw;

    const int NS = D_ / 32;   // 96
    #pragma unroll 4
    for (int s = 0; s < NS; ++s) {
        asm volatile("s_waitcnt vmcnt(6)" ::: "memory");    // stage s complete (s+1,s+2 in flight)
        __builtin_amdgcn_s_barrier();
        asm volatile("" ::: "memory");
        __builtin_amdgcn_sched_barrier(0);
        const int ps = (s + 3 < NS) ? (s + 3) : (NS - 1);   // clamp keeps vmcnt uniform
        STG((s + 3) & 3, ps);
        const char* pA = Ab + (s & 3) * 4096;
        const char* pB = Bb + (s & 3) * 8192;
        bf16x8 af[2], bq[4];
        #pragma unroll
        for (int i = 0; i < 2; ++i) af[i] = *(const bf16x8*)(pA + i * 1024);
        #pragma unroll
        for (int j = 0; j < 4; ++j) bq[j] = *(const bf16x8*)(pB + j * 1024);
        __builtin_amdgcn_s_setprio(1);
        #pragma unroll
        for (int mt = 0; mt < 2; ++mt)
            #pragma unroll
            for (int nt = 0; nt < 4; ++nt)
                acc[mt][nt] = __builtin_amdgcn_mfma_f32_16x16x32_bf16(af[mt], bq[nt], acc[mt][nt], 0, 0, 0);
        __builtin_amdgcn_s_setprio(0);
    }
#undef STG
    asm volatile("s_waitcnt vmcnt(0)" ::: "memory");   // drain clamped tail DMAs before LDS retire

    const int rq = g4 << 2;
    #pragma unroll
    for (int nt = 0; nt < 4; ++nt) {
        const int gcol = n0 + wn * 64 + nt * 16 + fr;
        const float bias = benc[e * C_ + gcol];
        #pragma unroll
        for (int mt = 0; mt < 2; ++mt)
            #pragma unroll
            for (int reg = 0; reg < 4; ++reg) {
                const int g = m0 + wm * 32 + mt * 16 + rq + reg;
                if (g < cnt) {
                    float v = acc[mt][nt][reg] + bias;
                    v = v > 0.f ? v : 0.f;
                    code[(size_t)(off + g) * C_ + gcol] = (__bf16)v;
                }
            }
    }
}

// =====================================================================
// dec: dec = code @ Wd16^T + bdec, scatter to original rows + fused loss.
// 128x128 tile, BK=32, 2-buffer LDS (32 KB) -> 4 blocks/CU (launch_bounds 256,4).
// d=1: vmcnt(0) -> barrier -> STG(s+1) -> reads. Epilogue (the dominant cost:
// 100 MB scattered stores + 50 MB imgG loads) gets 4-way block overlap.
// =====================================================================
__global__ __launch_bounds__(256, 4)
void dec_kernel(const __bf16* __restrict__ imgG, const __bf16* __restrict__ Wd16,
                const float* __restrict__ bdec, const int* __restrict__ row_ids,
                const int* __restrict__ counts, const int* __restrict__ offsets,
                const __bf16* __restrict__ code, float* __restrict__ decoded,
                double* __restrict__ loss_acc)
{
    const int e   = blockIdx.z;
    const int cnt = counts[e];
    const int m0  = blockIdx.y * 128;
    if (m0 >= cnt) return;
    const int off = offsets[e];
    const int n0  = blockIdx.x * 128;

    __shared__ __align__(16) __bf16 As[2][128][32];   // 16 KB
    __shared__ __align__(16) __bf16 Bs[2][128][32];   // 16 KB
    __shared__ float red[4];

    const int tid  = threadIdx.x;
    const int lane = tid & 63;
    const int wave = tid >> 6;
    const int wm   = wave >> 1;
    const int wn   = wave & 1;

    const int drow = tid >> 2;
    const int gsw  = (((tid & 3) ^ ((tid >> 3) & 3)) << 3);
    const __bf16* ag0 = code + (size_t)(off + m0 + drow) * C_ + gsw;
    const __bf16* ag1 = ag0 + (size_t)64 * C_;
    const __bf16* bg0 = Wd16 + ((size_t)e * D_ + n0 + drow) * C_ + gsw;
    const __bf16* bg1 = bg0 + (size_t)64 * C_;
    char* lA = (char*)As + tid * 16;
    char* lB = (char*)Bs + tid * 16;

#define STG(buf, step) do {                                  \
        const size_t ko_ = (size_t)(step) * 32;              \
        dma16(ag0 + ko_, lA + (buf) * 8192);                 \
        dma16(ag1 + ko_, lA + (buf) * 8192 + 4096);          \
        dma16(bg0 + ko_, lB + (buf) * 8192);                 \
        dma16(bg1 + ko_, lB + (buf) * 8192 + 4096);          \
    } while (0)

    STG(0, 0);

    floatx4 acc[4][4];
    #pragma unroll
    for (int i = 0; i < 4; ++i)
        #pragma unroll
        for (int j = 0; j < 4; ++j)
            acc[i][j] = (floatx4){0.f, 0.f, 0.f, 0.f};

    const int fr = lane & 15;
    const int g4 = lane >> 4;
    const int psw = ((g4 ^ ((fr >> 1) & 3)) << 4);
    const char* Ab = (const char*)As + (wm * 64 + fr) * 64 + psw;
    const char* Bb = (const char*)Bs + (wn * 64 + fr) * 64 + psw;

    const int NS = C_ / 32;   // 16
    #pragma unroll 4
    for (int s = 0; s < NS; ++s) {
        asm volatile("s_waitcnt vmcnt(0)" ::: "memory");    // own stage-s DMAs done
        __builtin_amdgcn_s_barrier();                       // all waves' DMAs + buf(s-1) reads done
        asm volatile("" ::: "memory");
        __builtin_amdgcn_sched_barrier(0);
        if (s + 1 < NS) STG((s + 1) & 1, s + 1);
        const char* pA = Ab + (s & 1) * 8192;
        const char* pB = Bb + (s & 1) * 8192;
        bf16x8 af[4], bq[4];
        #pragma unroll
        for (int i = 0; i < 4; ++i) {
            af[i] = *(const bf16x8*)(pA + i * 1024);
            bq[i] = *(const bf16x8*)(pB + i * 1024);
        }
        __builtin_amdgcn_s_setprio(1);
        #pragma unroll
        for (int mt = 0; mt < 4; ++mt)
            #pragma unroll
            for (int nt = 0; nt < 4; ++nt)
                acc[mt][nt] = __builtin_amdgcn_mfma_f32_16x16x32_bf16(af[mt], bq[nt], acc[mt][nt], 0, 0, 0);
        __builtin_amdgcn_s_setprio(0);
    }
#undef STG

    const int rq = g4 << 2;
    int orig[4][4];
    #pragma unroll
    for (int mt = 0; mt < 4; ++mt)
        #pragma unroll
        for (int reg = 0; reg < 4; ++reg) {
            const int g = m0 + wm * 64 + mt * 16 + rq + reg;
            orig[mt][reg] = (g < cnt) ? row_ids[off + g] : -1;
        }

    float lsum = 0.f;
    #pragma unroll
    for (int nt = 0; nt < 4; ++nt) {
        const int gcol = n0 + wn * 64 + nt * 16 + fr;
        const float bias = bdec[e * D_ + gcol];
        #pragma unroll
        for (int mt = 0; mt < 4; ++mt)
            #pragma unroll
            for (int reg = 0; reg < 4; ++reg) {
                if (orig[mt][reg] >= 0) {
                    const int g = m0 + wm * 64 + mt * 16 + rq + reg;
                    float v = acc[mt][nt][reg] + bias;
                    decoded[(size_t)orig[mt][reg] * D_ + gcol] = v;
                    float d = v - (float)imgG[(size_t)(off + g) * D_ + gcol];
                    lsum += d * d;
                }
            }
    }
    #pragma unroll
    for (int o = 32; o > 0; o >>= 1) lsum += __shfl_down(lsum, o, 64);
    if (lane == 0) red[wave] = lsum;
    __syncthreads();
    if (tid == 0) atomicAdd(loss_acc, (double)(red[0] + red[1] + red[2] + red[3]));
}

__global__ void k_final(const double* __restrict__ loss_acc, float* __restrict__ out) {
    if (threadIdx.x == 0 && blockIdx.x == 0)
        out[0] = (float)(*loss_acc / (double)((size_t)B_ * (size_t)D_));
}

// ---------------- launch ----------------
extern "C" void kernel_launch(void* const* d_in, const int* in_sizes, int n_in,
                              void* d_out, int out_size, void* d_ws, size_t ws_size,
                              hipStream_t stream)
{
    const float* img   = (const float*)d_in[0];
    const int*   label = (const int*)d_in[1];
    const float* Wenc  = (const float*)d_in[2];
    const float* benc  = (const float*)d_in[3];
    const float* Wdec  = (const float*)d_in[4];
    const float* bdec  = (const float*)d_in[5];
    float* out = (float*)d_out;

    char* ws = (char*)d_ws;
    int*    counts  = (int*)(ws + 0);
    int*    cursors = (int*)(ws + 32);
    int*    offsets = (int*)(ws + 64);
    double* loss    = (double*)(ws + 96);
    int*    row_ids = (int*)(ws + 128);
    // bf16 scratch (sizes include 128 rows of tail slack for OOB tile reads):
    __bf16* code = (__bf16*)(ws + 65536);                               // (B+128)*C*2 = 8,519,680
    __bf16* imgG = (__bf16*)(ws + 65536 + 8519680);                     // (B+128)*D*2 = 51,118,080
    __bf16* We16 = (__bf16*)(ws + 65536 + 8519680 + 51118080);          // E*C*D*2 = 25,165,824
    __bf16* Wd16 = (__bf16*)(ws + 65536 + 8519680 + 51118080 + 25165824);
    // total ws use ~105 MB

    hipMemsetAsync(d_ws, 0, 128, stream);
    k_count  <<<dim3(B_ / 256), dim3(256), 0, stream>>>(label, counts);
    k_offsets<<<dim3(1),        dim3(64),  0, stream>>>(counts, offsets);
    k_scatter<<<dim3(B_ / 256), dim3(256), 0, stream>>>(label, offsets, cursors, row_ids);
    k_prep   <<<dim3(2048),     dim3(256), 0, stream>>>(
        (const float4*)img, row_ids, (const float4*)Wenc, (const float4*)Wdec,
        (bf16x4*)imgG, (bf16x4*)We16, (bf16x4*)Wd16);
    enc_kernel<<<dim3(C_ / 128, B_ / 64, E_), dim3(256), 0, stream>>>(
        imgG, We16, benc, counts, offsets, code);
    dec_kernel<<<dim3(D_ / 128, B_ / 128, E_), dim3(256), 0, stream>>>(
        imgG, Wd16, bdec, row_ids, counts, offsets, code, out + 1, loss);
    k_final<<<dim3(1), dim3(64), 0, stream>>>(loss, out);
}